// Round 11
// baseline (69.266 us; speedup 1.0000x reference)
//
#include <hip/hip_runtime.h>
#include <hip/hip_bf16.h>
#include <cstddef>

// ---------------------------------------------------------------------------
// HardActor: fused regime-routed MLP (bf16 MFMA end-to-end)
//   h     = relu(x @ W1 + b1)            [B,256]
//   feats = relu(h @ W2 + b2)            [B,256]
//   raw   = feats @ Wh[regime] + bh[regime]   (regime = (int)x[:,255])
//   mean  = 0.1 * raw ; std = clip(exp(log_std),1e-3,1) broadcast
//
// R11: R10's swapped-operand structure (D^T = W^T act^T, proven correct and
// replay-stable) scaled to BM=128 with 16 waves/block (1024 threads).
// Rationale: R10 analysis showed the largest pipe after HBM is the per-block
// L2 re-read of all 512KB packed weights (1024 blocks -> 536MB ~ 37k cy/CU).
// BM=128 halves that to 268MB and halves barrier count per row; waves/SIMD
// stay 4 (16/CU, was 2 blocks x 8). LDS = 2 x 128 x 264 x 2B = 135KB static
// (1 block/CU; >64KB static is fine on gfx950 - R3 ran 68KB).
// G3 runs as two bt-half passes so acc stays 32 regs (no-spill budget ~90
// regs, cap 128 at launch_bounds(1024,4)). Regime read per-lane from global
// x before each pass's MFMA loop (R10-proven, no LDS broadcast).
// ---------------------------------------------------------------------------

typedef unsigned short u16;
typedef unsigned int   u32;

using bf16x8 = __attribute__((ext_vector_type(8))) __bf16;
using f32x4  = __attribute__((ext_vector_type(4))) float;

#define BM      128
#define LDSW    264   // 256 + 8 bf16 pad; 528B row pitch (16B-aligned rows)
#define THREADS 1024

__device__ __forceinline__ u16 f2bf(float f) {
  return __builtin_bit_cast(u16, (__bf16)f);   // native v_cvt (RNE)
}

// Packed ws layout (u16 elements), A-frag order (A = W^T), 16-wave split:
//  frag (16x16x32): lane l, elem j -> W^T[n = base+(l&15)][k = kk*32+(l>>4)*8+j]
//  W1p [0)      : [w:16][kk:8][lane:64][j:8]        (65536)  n = w*16+(l&15)
//  W2p [65536)  : same                               (65536)
//  Whp [131072) : [w:16][nb:2][kk:8][lane:64][j:8]  (131072) c = w*32+nb*16+(l&15)
//                 c in [0,512): head=c>>7, a=c&127
__global__ void prep_weights(const float* __restrict__ W1,
                             const float* __restrict__ W2,
                             const float* __restrict__ Wh,
                             u16* __restrict__ ws) {
  int i = blockIdx.x * 256 + threadIdx.x;          // [0, 65536)
  {
    int j  = i & 7, l = (i >> 3) & 63, kk = (i >> 9) & 7;
    int w  = (i >> 12) & 15;
    int n = w * 16 + (l & 15);
    int k = kk * 32 + ((l >> 4) << 3) + j;
    ws[i]         = f2bf(W1[k * 256 + n]);
    ws[65536 + i] = f2bf(W2[k * 256 + n]);
  }
#pragma unroll
  for (int t = 0; t < 2; ++t) {
    int idx = i + t * 65536;                        // [0, 131072)
    int j  = idx & 7, l = (idx >> 3) & 63, kk = (idx >> 9) & 7;
    int nb = (idx >> 12) & 1, w = (idx >> 13) & 15;
    int c = w * 32 + nb * 16 + (l & 15);            // col in [0,512)
    int k = kk * 32 + ((l >> 4) << 3) + j;
    ws[131072 + idx] = f2bf(Wh[(c >> 7) * 32768 + k * 128 + (c & 127)]);
  }
}

__device__ __forceinline__ f32x4 mfma16(bf16x8 a, bf16x8 b, f32x4 c) {
  return __builtin_amdgcn_mfma_f32_16x16x32_bf16(a, b, c, 0, 0, 0);
}

// One swapped layer slice: out^T[n][b], n in wave's 16 cols, b over 128 rows.
// act/outbuf: LDS [128][LDSW] bf16 [batch][feature]. Wp: wave's packed weights.
__device__ __forceinline__ void gemm_swapped16(const u16* __restrict__ act,
                                               const u16* __restrict__ Wp,
                                               const float* __restrict__ bias,
                                               u16* __restrict__ outbuf,
                                               int w, int ll, int lh, int lane) {
  f32x4 acc[8] = {};
#pragma unroll
  for (int kk = 0; kk < 8; ++kk) {
    bf16x8 a = *(const bf16x8*)&Wp[(kk * 64 + lane) * 8];
    bf16x8 b[8];
#pragma unroll
    for (int bt = 0; bt < 8; ++bt)
      b[bt] = *(const bf16x8*)&act[(bt * 16 + ll) * LDSW + kk * 32 + lh * 8];
#pragma unroll
    for (int bt = 0; bt < 8; ++bt)
      acc[bt] = mfma16(a, b[bt], acc[bt]);
  }
  const int n0 = w * 16 + lh * 4;                  // output feature base (4 consec)
  const float4 bv = *(const float4*)&bias[n0];
#pragma unroll
  for (int bt = 0; bt < 8; ++bt) {
    ushort4 o;
    o.x = f2bf(fmaxf(acc[bt][0] + bv.x, 0.f));
    o.y = f2bf(fmaxf(acc[bt][1] + bv.y, 0.f));
    o.z = f2bf(fmaxf(acc[bt][2] + bv.z, 0.f));
    o.w = f2bf(fmaxf(acc[bt][3] + bv.w, 0.f));
    *(ushort4*)&outbuf[(bt * 16 + ll) * LDSW + n0] = o;
  }
}

__global__ __launch_bounds__(THREADS, 4) void actor_main(
    const float* __restrict__ x,
    const float* __restrict__ b1, const float* __restrict__ b2,
    const float* __restrict__ bh, const float* __restrict__ log_std,
    const u16* __restrict__ wbf,
    float* __restrict__ out_mean, float* __restrict__ out_std) {
  __shared__ u16 bufX[BM * LDSW];   // x (bf16), later feats
  __shared__ u16 bufH[BM * LDSW];   // h

  const int tid  = threadIdx.x;
  const int lane = tid & 63;
  const int w    = tid >> 6;           // wave 0..15
  const int ll   = lane & 15;          // batch-col within 16-tile
  const int lh   = lane >> 4;          // 0..3
  const int row0 = blockIdx.x * BM;

  // ---- stage x -> bf16 LDS [batch][feature] ----
  {
    const float4* xg = (const float4*)(x + (size_t)row0 * 256);
#pragma unroll
    for (int it = 0; it < 8; ++it) {               // 128 rows x 64 float4 / 1024
      const int i = tid + it * THREADS;
      float4 v = xg[i];
      int row = i >> 6, c4 = (i & 63) << 2;
      ushort4 b;
      b.x = f2bf(v.x); b.y = f2bf(v.y); b.z = f2bf(v.z); b.w = f2bf(v.w);
      *(ushort4*)&bufX[row * LDSW + c4] = b;
    }
  }

  // ---- std writes (independent; overlap the barrier wait) ----
  {
    const int c4 = (tid & 31) << 2;
    float4 s;
    s.x = fminf(fmaxf(expf(log_std[c4 + 0]), 1e-3f), 1.0f);
    s.y = fminf(fmaxf(expf(log_std[c4 + 1]), 1e-3f), 1.0f);
    s.z = fminf(fmaxf(expf(log_std[c4 + 2]), 1e-3f), 1.0f);
    s.w = fminf(fmaxf(expf(log_std[c4 + 3]), 1e-3f), 1.0f);
#pragma unroll
    for (int i = tid; i < BM * 32; i += THREADS) {   // 4 iters
      int row = i >> 5;
      *(float4*)&out_std[(size_t)(row0 + row) * 128 + c4] = s;
    }
  }
  __syncthreads();

  // ---- G1: h^T = W1^T x^T  (reads bufX, writes bufH) ----
  gemm_swapped16(bufX, wbf + w * 4096, b1, bufH, w, ll, lh, lane);
  __syncthreads();

  // ---- G2: feats^T = W2^T h^T  (reads bufH, writes bufX) ----
  gemm_swapped16(bufH, wbf + 65536 + w * 4096, b2, bufX, w, ll, lh, lane);
  __syncthreads();

  // ---- G3: raw^T = Wh^T feats^T; wave w owns 32 of 512 concat cols
  //      (head = w>>2). Two bt-half passes keep acc at 32 regs. ----
  {
    const u16* __restrict__ Wp3 = wbf + 131072 + w * 8192;
    const int head = w >> 2;
#pragma unroll 1
    for (int p = 0; p < 2; ++p) {
      const int rbase = p * 64;                    // row base of this half

      // per-lane regime for this pass's 4 rows (issued before MFMA loop)
      int rg[4];
#pragma unroll
      for (int bt = 0; bt < 4; ++bt)
        rg[bt] = (int)x[(size_t)(row0 + rbase + bt * 16 + ll) * 256 + 255];

      f32x4 acc[2][4] = {};
#pragma unroll
      for (int kk = 0; kk < 8; ++kk) {
        bf16x8 b[4];
#pragma unroll
        for (int bt = 0; bt < 4; ++bt)
          b[bt] = *(const bf16x8*)&bufX[(rbase + bt * 16 + ll) * LDSW + kk * 32 + lh * 8];
#pragma unroll
        for (int nb = 0; nb < 2; ++nb) {
          bf16x8 a = *(const bf16x8*)&Wp3[((nb * 8 + kk) * 64 + lane) * 8];
#pragma unroll
          for (int bt = 0; bt < 4; ++bt)
            acc[nb][bt] = mfma16(a, b[bt], acc[nb][bt]);
        }
      }
#pragma unroll
      for (int nb = 0; nb < 2; ++nb) {
        const int acol = (w & 3) * 32 + nb * 16 + lh * 4;   // 0..127 within head
        const float4 bhv = *(const float4*)&bh[head * 128 + acol];
#pragma unroll
        for (int bt = 0; bt < 4; ++bt) {
          const int brow = rbase + bt * 16 + ll;
          if (rg[bt] == head) {
            float4 o;
            o.x = 0.1f * (acc[nb][bt][0] + bhv.x);
            o.y = 0.1f * (acc[nb][bt][1] + bhv.y);
            o.z = 0.1f * (acc[nb][bt][2] + bhv.z);
            o.w = 0.1f * (acc[nb][bt][3] + bhv.w);
            *(float4*)&out_mean[(size_t)(row0 + brow) * 128 + acol] = o;
          }
        }
      }
    }
  }
}

extern "C" void kernel_launch(void* const* d_in, const int* in_sizes, int n_in,
                              void* d_out, int out_size, void* d_ws, size_t ws_size,
                              hipStream_t stream) {
  const float* x  = (const float*)d_in[0];
  const float* W1 = (const float*)d_in[1];
  const float* b1 = (const float*)d_in[2];
  const float* W2 = (const float*)d_in[3];
  const float* b2 = (const float*)d_in[4];
  const float* Wh = (const float*)d_in[5];
  const float* bh = (const float*)d_in[6];
  const float* ls = (const float*)d_in[7];

  const int B = in_sizes[0] / 256;          // 65536
  float* out_mean = (float*)d_out;
  float* out_std  = out_mean + (size_t)B * 128;
  u16* wbf = (u16*)d_ws;                    // needs 512 KiB

  hipLaunchKernelGGL(prep_weights, dim3(256), dim3(256), 0, stream, W1, W2, Wh, wbf);
  hipLaunchKernelGGL(actor_main, dim3(B / BM), dim3(THREADS), 0, stream,
                     x, b1, b2, bh, ls, wbf, out_mean, out_std);
}